// Round 1
// baseline (188.121 us; speedup 1.0000x reference)
//
#include <hip/hip_runtime.h>

// Legendre projection: out[n, dim*128 + deg] = P_deg(2*x[n,dim] - 1)
// N_POINTS = 524288, INPUT_DIM = 2, MAX_DEGREE = 127 -> 128 degrees.
// Output: 524288 * 256 fp32 = 512 MiB  => HBM-write-bound (~85 us floor).

#define DEG1 128  // MAX_DEGREE + 1

__global__ __launch_bounds__(256) void LegendreProjection_48644799594943_kernel(
    const float* __restrict__ x, float* __restrict__ out, int total) {
    int idx = blockIdx.x * blockDim.x + threadIdx.x;  // one thread per (n, dim)
    if (idx >= total) return;

    float xs = 2.0f * x[idx] - 1.0f;

    float4* o = reinterpret_cast<float4*>(out) + (size_t)idx * (DEG1 / 4);

    float pm = 1.0f;  // P_{deg-1}
    float pc = xs;    // P_deg (after deg>=1 computed)

#pragma unroll
    for (int vec = 0; vec < DEG1 / 4; ++vec) {
        float vv[4];
#pragma unroll
        for (int j = 0; j < 4; ++j) {
            const int deg = vec * 4 + j;
            float val;
            if (deg == 0) {
                val = 1.0f;
            } else if (deg == 1) {
                val = xs;
            } else {
                // P_{n+1} = ((2n+1) x P_n - n P_{n-1}) / (n+1), n = deg-1
                const float nf = (float)(deg - 1);
                val = ((2.0f * nf + 1.0f) * xs * pc - nf * pm) * (1.0f / (nf + 1.0f));
                pm = pc;
                pc = val;
            }
            vv[j] = val;
        }
        float4 v;
        v.x = vv[0]; v.y = vv[1]; v.z = vv[2]; v.w = vv[3];
        o[vec] = v;
    }
}

extern "C" void kernel_launch(void* const* d_in, const int* in_sizes, int n_in,
                              void* d_out, int out_size, void* d_ws, size_t ws_size,
                              hipStream_t stream) {
    const float* x = (const float*)d_in[0];
    float* out = (float*)d_out;
    const int total = in_sizes[0];  // N_POINTS * INPUT_DIM = 1,048,576
    const int block = 256;
    const int grid = (total + block - 1) / block;
    LegendreProjection_48644799594943_kernel<<<grid, block, 0, stream>>>(x, out, total);
}

// Round 2
// 109.471 us; speedup vs baseline: 1.7184x; 1.7184x over previous
//
#include <hip/hip_runtime.h>

// Legendre projection: out[n, dim*128 + deg] = P_deg(2*x[n,dim] - 1)
// N_POINTS = 524288, INPUT_DIM = 2, 128 degrees -> 512 MiB fp32 output.
// HBM-write-bound; round 1 (per-thread 512B segments, strided wave stores)
// hit 2.9 TB/s. This round: LDS-staged coalesced drain (1 KB contiguous
// per wave-store instruction).

#define DEG1 128  // MAX_DEGREE + 1

__global__ __launch_bounds__(256) void LegendreProjection_48644799594943_kernel(
    const float* __restrict__ x, float* __restrict__ out) {
    // 64 segments * 32 float4 = 32 KB. Swizzled: [seg][vec ^ (seg&7)]
    __shared__ float4 lds[64 * 32];

    const int tid = threadIdx.x;
    const int seg0 = blockIdx.x * 64;  // first (n,dim) segment of this block

    // --- compute phase: threads 0..63 each own one segment ---
    if (tid < 64) {
        const int seg = tid;
        const float xs = 2.0f * x[seg0 + seg] - 1.0f;
        float4* row = &lds[seg * 32];
        const int sw = seg & 7;

        float pm = 1.0f;  // P_{deg-1}
        float pc = xs;    // P_deg
#pragma unroll
        for (int vec = 0; vec < 32; ++vec) {
            float vv[4];
#pragma unroll
            for (int j = 0; j < 4; ++j) {
                const int deg = vec * 4 + j;
                float val;
                if (deg == 0) {
                    val = 1.0f;
                } else if (deg == 1) {
                    val = xs;
                } else {
                    // P_{n+1} = ((2n+1) x P_n - n P_{n-1}) / (n+1), n = deg-1
                    const float nf = (float)(deg - 1);
                    val = ((2.0f * nf + 1.0f) * xs * pc - nf * pm) * (1.0f / (nf + 1.0f));
                    pm = pc;
                    pc = val;
                }
                vv[j] = val;
            }
            float4 v;
            v.x = vv[0]; v.y = vv[1]; v.z = vv[2]; v.w = vv[3];
            row[vec ^ sw] = v;  // XOR swizzle: stride-512B writes -> ~2-way banks
        }
    }

    __syncthreads();

    // --- drain phase: 32 KB contiguous, all 256 threads ---
    // Per wave-instruction: 64 lanes * float4 = 1 KB contiguous.
    float4* dst = reinterpret_cast<float4*>(out) + (size_t)seg0 * (DEG1 / 4);
#pragma unroll
    for (int i = 0; i < 8; ++i) {
        const int L = i * 256 + tid;   // float4 index within the 2048-float4 tile
        const int seg = L >> 5;        // 32 float4 per segment
        const int vec = L & 31;
        dst[L] = lds[seg * 32 + (vec ^ (seg & 7))];
    }
}

extern "C" void kernel_launch(void* const* d_in, const int* in_sizes, int n_in,
                              void* d_out, int out_size, void* d_ws, size_t ws_size,
                              hipStream_t stream) {
    const float* x = (const float*)d_in[0];
    float* out = (float*)d_out;
    const int total = in_sizes[0];      // 1,048,576 (n,dim) segments
    const int grid = total / 64;        // 64 segments per block (total % 64 == 0)
    LegendreProjection_48644799594943_kernel<<<grid, 256, 0, stream>>>(x, out);
}

// Round 4
// 102.164 us; speedup vs baseline: 1.8414x; 1.0715x over previous
//
#include <hip/hip_runtime.h>

// Legendre projection: out[n, dim*128 + deg] = P_deg(2*x[n,dim] - 1)
// 1,048,576 (n,dim) segments x 128 fp32 degrees = 512 MiB output. Write-bound.
// Round 2 (block-barrier LDS staging): 109.5 us @ ~4.9 TB/s.
// Round 4: barrier-free per-wave pipeline (round 3 + native-vector fix for
// __builtin_nontemporal_store). Each wave owns 64 segments, 4 chunks of 32
// degrees: compute -> swizzled LDS write -> transposed LDS read ->
// nontemporal stores (each wave-instr = 8 aligned full 128B lines).
// Only intra-wave waitcnts; stores overlap next chunk's compute.

#define DEG1 128

typedef float f32x4 __attribute__((ext_vector_type(4)));

__global__ __launch_bounds__(256) void LegendreProjection_48644799594943_kernel(
    const float* __restrict__ x, float* __restrict__ out) {
    // [wave][seg][slot], slot = vec ^ (seg&7). 4 * 64 * 8 * 16B = 32 KB.
    __shared__ f32x4 lds[4][64][8];

    const int tid  = threadIdx.x;
    const int wave = tid >> 6;
    const int lane = tid & 63;
    const int seg0 = (blockIdx.x * 4 + wave) * 64;  // this wave's 64 segments

    const float xs = 2.0f * x[seg0 + lane] - 1.0f;

    f32x4 (*my)[8] = lds[wave];
    f32x4* outv = reinterpret_cast<f32x4*>(out);

    float pm = 1.0f;  // P_{deg-1}
    float pc = xs;    // P_deg

#pragma unroll
    for (int c = 0; c < 4; ++c) {
        // --- compute 32 degrees for my segment, write swizzled to LDS ---
#pragma unroll
        for (int v = 0; v < 8; ++v) {
            f32x4 q;
#pragma unroll
            for (int j = 0; j < 4; ++j) {
                const int deg = c * 32 + v * 4 + j;
                float val;
                if (deg == 0) {
                    val = 1.0f;
                } else if (deg == 1) {
                    val = xs;
                } else {
                    // P_{n+1} = ((2n+1) x P_n - n P_{n-1}) / (n+1), n = deg-1
                    const float nf = (float)(deg - 1);
                    val = ((2.0f * nf + 1.0f) * xs * pc - nf * pm) * (1.0f / (nf + 1.0f));
                    pm = pc;
                    pc = val;
                }
                q[j] = val;
            }
            my[lane][v ^ (lane & 7)] = q;  // aligned 8-lane runs hit 8 distinct bank groups
        }

        // --- transposed drain: 8 wave-instrs, each = 8 aligned full 128B lines ---
#pragma unroll
        for (int k = 0; k < 8; ++k) {
            const int s = k * 8 + (lane >> 3);  // local segment
            const int v = lane & 7;             // float4 index within chunk
            const f32x4 q = my[s][v ^ (s & 7)];
            // out float4 index: seg*(128/4) + chunk*8 + v ; 8 lanes -> 128B contiguous
            __builtin_nontemporal_store(q, &outv[(size_t)(seg0 + s) * (DEG1 / 4) + c * 8 + v]);
        }
    }
}

extern "C" void kernel_launch(void* const* d_in, const int* in_sizes, int n_in,
                              void* d_out, int out_size, void* d_ws, size_t ws_size,
                              hipStream_t stream) {
    const float* x = (const float*)d_in[0];
    float* out = (float*)d_out;
    const int total = in_sizes[0];   // 1,048,576 segments
    const int grid = total / 256;    // 256 segments per block (4 waves x 64)
    LegendreProjection_48644799594943_kernel<<<grid, 256, 0, stream>>>(x, out);
}